// Round 2
// baseline (609.702 us; speedup 1.0000x reference)
//
#include <hip/hip_runtime.h>
#include <hip/hip_bf16.h>

// BahdanauAttention: B=32, S=2048, H=1024, U=1024
//   q2 = query@W2 + b2                                  [B,U]
//   score[b,s] = sum_u tanh(values[b,s]@W1[:,u] + b1[u] + q2[b,u]) * V[u]
//   attn = softmax_s(score); context = sum_s attn * values
//
// R6 = R5 resubmit (R5 died to container infra, no signal).
// score GEMM: 256x256-tile BK=32 pipelined kernel (counted vmcnt(8), 4 LDS
// buffers, T2 source-side XOR swizzle, T5 setprio), fed by a one-time
// values->bf16 convert fused into prep so BOTH operands stage via
// global_load_lds. Falls back to the proven R4 path if ws_size < 130.4 MB.

#define B_ 32
#define S_ 2048
#define H_ 1024
#define U_ 1024
#define M_ (B_ * S_)   // 65536
#define NT_ 32         // K-tiles of 32 in score_gemm8

typedef __bf16 bf16;
typedef __bf16 bf16x8 __attribute__((ext_vector_type(8)));
typedef float  f32x4  __attribute__((ext_vector_type(4)));

__device__ __forceinline__ void gl2lds16(const void* g, void* l) {
    __builtin_amdgcn_global_load_lds(
        (const __attribute__((address_space(1))) void*)g,
        (__attribute__((address_space(3))) void*)l, 16, 0, 0);
}

__device__ __forceinline__ bf16x8 cvt8(float4 a, float4 b) {
    bf16x8 o;
    o[0] = (bf16)a.x; o[1] = (bf16)a.y; o[2] = (bf16)a.z; o[3] = (bf16)a.w;
    o[4] = (bf16)b.x; o[5] = (bf16)b.y; o[6] = (bf16)b.z; o[7] = (bf16)b.w;
    return o;
}

// ---------------- prep: W1 transpose-cast (0..255) + q2 (256..767) + values->bf16 (768..) ----
__global__ void prep_kernel(const float* __restrict__ W1, bf16* __restrict__ W1T,
                            const float* __restrict__ query, const float* __restrict__ W2,
                            const float* __restrict__ b2, float* __restrict__ q2,
                            const float* __restrict__ values, bf16* __restrict__ vbf) {
    __shared__ __align__(16) char smem[64 * 65 * 2];   // 8320 B, union of uses
    int tid = threadIdx.x;
    if (blockIdx.x < 256) {
        // ---- W1 [H,U] fp32 -> W1T [U,H] bf16 ----
        bf16* t = (bf16*)smem;
        int h0 = (blockIdx.x >> 4) * 64, u0 = (blockIdx.x & 15) * 64;
        #pragma unroll
        for (int i = 0; i < 16; ++i) {
            int idx = i * 256 + tid;
            int r = idx >> 6, c = idx & 63;
            t[c * 65 + r] = (bf16)W1[(long)(h0 + r) * U_ + u0 + c];
        }
        __syncthreads();
        #pragma unroll
        for (int i = 0; i < 16; ++i) {
            int idx = i * 256 + tid;
            int r = idx >> 6, c = idx & 63;
            W1T[(long)(u0 + r) * H_ + h0 + c] = t[r * 65 + c];
        }
    } else if (blockIdx.x < 768) {
        // ---- q2 = query@W2 + b2 ----
        float* qsh  = (float*)smem;            // 4 KB
        float* part = (float*)(smem + 4096);   // 4x64 f32 = 1 KB
        int idx = blockIdx.x - 256;            // 0..511
        int b  = idx >> 4;
        int u0 = (idx & 15) * 64;
        int ul = tid & 63, kc = tid >> 6;
        for (int i = tid; i < H_; i += 256) qsh[i] = query[b * H_ + i];
        __syncthreads();
        float acc = 0.f;
        const float* wp = W2 + (long)(kc * 256) * U_ + u0 + ul;
        #pragma unroll 8
        for (int h = 0; h < 256; ++h) acc += qsh[kc * 256 + h] * wp[(long)h * U_];
        part[kc * 64 + ul] = acc;
        __syncthreads();
        if (tid < 64)
            q2[b * U_ + u0 + tid] = part[tid] + part[64 + tid] + part[128 + tid]
                                    + part[192 + tid] + b2[u0 + tid];
    } else {
        // ---- values f32 [M,H] -> bf16 [M,H] ----
        long cid = (long)(blockIdx.x - 768) * 256 + tid;
        const long stride = 4096L * 256;
        const long n8 = (long)M_ * H_ / 8;     // 8M chunks of 8 elems
        for (long c = cid; c < n8; c += stride) {
            const float4* s = reinterpret_cast<const float4*>(values + c * 8);
            float4 a = s[0], b = s[1];
            *reinterpret_cast<bf16x8*>(vbf + c * 8) = cvt8(a, b);
        }
    }
}

// ---------------- fused GEMM + tanh + dot(V): 256x256 tile, BK=32, pipelined ------------
// 512 thr / 8 waves (2M x 4N), per-wave 128x64 C. LDS 128 KiB = 4 buffers x
// (A 16KB + B 16KB). Staging runs 3 K-tiles ahead of compute; s_waitcnt
// vmcnt(8) once per tile (counted, never 0 in steady state). 16B k-slots are
// XOR-swizzled slot^=(row>>1)&3 via pre-swizzled GLOBAL source (linear LDS
// dest, required by global_load_lds) + matching swizzled ds_read addresses:
// fragment reads are exactly conflict-free (8 words/bank for the 1KB wave read).
__global__ __launch_bounds__(512, 2) void score_gemm8(
    const bf16* __restrict__ A,    // vbf [M,H]
    const bf16* __restrict__ BT,   // W1T bf16 [U,H]
    const float* __restrict__ b1, const float* __restrict__ q2,
    const float* __restrict__ V, float* __restrict__ score /* [M] pre-zeroed */)
{
    __shared__ __align__(16) bf16 lds[65536];          // 128 KiB
    const int tid  = threadIdx.x;
    const int lane = tid & 63;
    const int wave = tid >> 6;                         // 0..7
    const int wm = wave >> 2, wn = wave & 3;
    const int lrow = lane & 15, quad = lane >> 4;

    // XCD swizzle: 4 n-tiles of the same 256-row A-panel land consecutively on one XCD
    const int xcd = blockIdx.x & 7;
    const int j   = blockIdx.x >> 3;                   // 0..127
    const int mt  = xcd * 32 + (j >> 2);               // 0..255
    const int nt  = j & 3;
    const long m0 = (long)mt * 256;
    const int  n0 = nt * 256;

    // staging sources (per-lane, pre-swizzled): lane l covers (row wave*16+l/4, phys slot l&3)
    const int rs = wave * 16 + (lane >> 2);
    const int sl = (lane & 3) ^ ((lane >> 3) & 3);     // logical slot for phys slot l&3
    const bf16* a0  = A  + (m0 + rs) * H_ + sl * 8;
    const bf16* a1  = a0 + 128 * H_;
    const bf16* bt0 = BT + (long)(n0 + rs) * H_ + sl * 8;
    const bf16* bt1 = bt0 + 128 * H_;

    // fragment read offsets (elems); kse applies the matching read-side swizzle
    const int kse  = (quad ^ ((lrow >> 1) & 3)) * 8;
    const int aoff = (wm * 128 + lrow) * 32 + kse;
    const int boff = 8192 + (wn * 64 + lrow) * 32 + kse;

    f32x4 acc[8][4];
    const f32x4 zero = {0.f, 0.f, 0.f, 0.f};
    #pragma unroll
    for (int mi = 0; mi < 8; ++mi)
        #pragma unroll
        for (int ni = 0; ni < 4; ++ni) acc[mi][ni] = zero;

    // prologue: stage tiles 0..2 into buffers 0..2 (12 loads), wait tile 0 (leave 8)
    for (int tt = 0; tt < 3; ++tt) {
        bf16* d = lds + tt * 16384 + wave * 512;
        gl2lds16(a0  + tt * 32, d);
        gl2lds16(a1  + tt * 32, d + 4096);
        gl2lds16(bt0 + tt * 32, d + 8192);
        gl2lds16(bt1 + tt * 32, d + 8192 + 4096);
    }
    __builtin_amdgcn_sched_barrier(0);
    asm volatile("s_waitcnt vmcnt(8)" ::: "memory");
    __builtin_amdgcn_s_barrier();
    __builtin_amdgcn_sched_barrier(0);

    #pragma unroll 1
    for (int t = 0; t < NT_; ++t) {
        const bf16* buf = lds + (t & 3) * 16384;
        // ---------- phase 0: stage A(t+3); compute mi 0..3 ----------
        if (t + 3 < NT_) {
            bf16* d = lds + ((t + 3) & 3) * 16384 + wave * 512;
            gl2lds16(a0 + (t + 3) * 32, d);
            gl2lds16(a1 + (t + 3) * 32, d + 4096);
        }
        bf16x8 af[4], bg[4];
        #pragma unroll
        for (int ni = 0; ni < 4; ++ni)
            bg[ni] = *reinterpret_cast<const bf16x8*>(buf + boff + ni * 512);
        #pragma unroll
        for (int mi = 0; mi < 4; ++mi)
            af[mi] = *reinterpret_cast<const bf16x8*>(buf + aoff + mi * 512);
        __builtin_amdgcn_s_setprio(1);
        #pragma unroll
        for (int mi = 0; mi < 4; ++mi)
            #pragma unroll
            for (int ni = 0; ni < 4; ++ni)
                acc[mi][ni] = __builtin_amdgcn_mfma_f32_16x16x32_bf16(
                    af[mi], bg[ni], acc[mi][ni], 0, 0, 0);
        __builtin_amdgcn_s_setprio(0);
        __builtin_amdgcn_sched_barrier(0);
        __builtin_amdgcn_s_barrier();
        __builtin_amdgcn_sched_barrier(0);
        // ---------- phase 1: stage B(t+3); compute mi 4..7 ----------
        if (t + 3 < NT_) {
            bf16* d = lds + ((t + 3) & 3) * 16384 + 8192 + wave * 512;
            gl2lds16(bt0 + (t + 3) * 32, d);
            gl2lds16(bt1 + (t + 3) * 32, d + 4096);
        }
        #pragma unroll
        for (int mi = 0; mi < 4; ++mi)
            af[mi] = *reinterpret_cast<const bf16x8*>(buf + aoff + (4 + mi) * 512);
        __builtin_amdgcn_s_setprio(1);
        #pragma unroll
        for (int mi = 0; mi < 4; ++mi)
            #pragma unroll
            for (int ni = 0; ni < 4; ++ni)
                acc[4 + mi][ni] = __builtin_amdgcn_mfma_f32_16x16x32_bf16(
                    af[mi], bg[ni], acc[4 + mi][ni], 0, 0, 0);
        __builtin_amdgcn_s_setprio(0);
        __builtin_amdgcn_sched_barrier(0);
        // counted wait: next-consumed tile (t+1) landed; 8 loads (2 tiles) stay in flight
        if (t < NT_ - 3)       asm volatile("s_waitcnt vmcnt(8)" ::: "memory");
        else if (t == NT_ - 3) asm volatile("s_waitcnt vmcnt(4)" ::: "memory");
        else if (t == NT_ - 2) asm volatile("s_waitcnt vmcnt(0)" ::: "memory");
        __builtin_amdgcn_s_barrier();
        __builtin_amdgcn_sched_barrier(0);
    }

    // epilogue: tanh(acc + b1 + q2) * V, reduce over u (16 lanes), atomic into score
    const int bb = (int)(m0 / S_);
    float bq[4], vv[4];
    #pragma unroll
    for (int ni = 0; ni < 4; ++ni) {
        int u = n0 + wn * 64 + ni * 16 + lrow;
        bq[ni] = b1[u] + q2[bb * U_ + u];
        vv[ni] = V[u];
    }
    #pragma unroll
    for (int mi = 0; mi < 8; ++mi) {
        #pragma unroll
        for (int r = 0; r < 4; ++r) {
            float s = 0.f;
            #pragma unroll
            for (int ni = 0; ni < 4; ++ni) {
                float x = acc[mi][ni][r] + bq[ni];
                float th = 1.f - 2.f / (__expf(2.f * x) + 1.f);   // tanh
                s += th * vv[ni];
            }
            s += __shfl_xor(s, 1); s += __shfl_xor(s, 2);
            s += __shfl_xor(s, 4); s += __shfl_xor(s, 8);
            if (lrow == 0)
                atomicAdd(score + m0 + wm * 128 + mi * 16 + quad * 4 + r, s);
        }
    }
}

// ---------------- FALLBACK fused GEMM (proven R4 kernel, used when ws too small) ------------
#define ASTRIDE 40   // bf16 elems per A row in LDS (32 used + 8 pad)
__global__ __launch_bounds__(256, 3) void score_gemm(
    const float* __restrict__ A32,  // values fp32 [M,H]
    const bf16* __restrict__ BT,    // W1T bf16 [U,H]
    const float* __restrict__ b1, const float* __restrict__ q2,
    const float* __restrict__ V, float* __restrict__ score /* [M] pre-zeroed */)
{
    __shared__ __align__(16) bf16 a_sh[2 * 128 * ASTRIDE];   // 20 KB
    __shared__ __align__(16) bf16 b_sh[2 * 128 * 32];        // 16 KB
    const int tid  = threadIdx.x;
    const int lane = tid & 63;
    const int wave = tid >> 6;
    const int wm = wave >> 1, wn = wave & 1;
    const int xcd = blockIdx.x & 7;
    const int i_  = blockIdx.x >> 3;
    const int nt  = i_ & 7;
    const int mt  = xcd * 64 + (i_ >> 3);
    const long m0 = (long)mt * 128;
    const int  n0 = nt * 128;
    const int lrow = lane & 15;
    const int quad = lane >> 4;
    const int arow = tid >> 1;
    const int aseg = tid & 1;

    f32x4 acc[4][4];
    const f32x4 zero = {0.f, 0.f, 0.f, 0.f};
    #pragma unroll
    for (int mi = 0; mi < 4; ++mi)
        #pragma unroll
        for (int ni = 0; ni < 4; ++ni) acc[mi][ni] = zero;

    const float* Abase = A32 + m0 * H_;
    const bf16*  Bbase = BT + (long)n0 * H_;

    for (int kt = 0; kt < H_; kt += 64) {
        #pragma unroll
        for (int i = 0; i < 4; ++i) {
            int g  = i * 4 + wave;
            int hs = g >> 3, q = g & 7;
            int row = q * 16 + (lane >> 2);
            int gc  = (lane & 3) ^ ((row >> 1) & 3);
            gl2lds16(Bbase + (long)row * H_ + kt + hs * 32 + gc * 8,
                     (void*)(b_sh + hs * 4096 + q * 512));
        }
        float4 av[2][4];
        #pragma unroll
        for (int hs = 0; hs < 2; ++hs) {
            const float4* src = reinterpret_cast<const float4*>(
                Abase + (long)arow * H_ + kt + hs * 32 + aseg * 16);
            av[hs][0] = src[0]; av[hs][1] = src[1];
            av[hs][2] = src[2]; av[hs][3] = src[3];
        }
        #pragma unroll
        for (int hs = 0; hs < 2; ++hs) {
            bf16* dst = a_sh + hs * (128 * ASTRIDE) + arow * ASTRIDE + aseg * 16;
            *reinterpret_cast<bf16x8*>(dst)     = cvt8(av[hs][0], av[hs][1]);
            *reinterpret_cast<bf16x8*>(dst + 8) = cvt8(av[hs][2], av[hs][3]);
        }
        __syncthreads();

        #pragma unroll
        for (int hs = 0; hs < 2; ++hs) {
            bf16x8 af[4], bg[4];
            #pragma unroll
            for (int mi = 0; mi < 4; ++mi) {
                int r = wm * 64 + mi * 16 + lrow;
                af[mi] = *reinterpret_cast<const bf16x8*>(
                    a_sh + hs * (128 * ASTRIDE) + r * ASTRIDE + quad * 8);
            }
            #pragma unroll
            for (int ni = 0; ni < 4; ++ni) {
                int r = wn * 64 + ni * 16 + lrow;
                int p = quad ^ ((r >> 1) & 3);
                bg[ni] = *reinterpret_cast<const bf16x8*>(
                    b_sh + hs * 4096 + r * 32 + p * 8);
            }
            #pragma unroll
            for (int mi = 0; mi < 4; ++mi)
                #pragma unroll
                for (int ni = 0; ni < 4; ++ni)
                    acc[mi][ni] = __builtin_amdgcn_mfma_f32_16x16x32_bf16(
                        af[mi], bg[ni], acc[mi][ni], 0, 0, 0);
        }
        __syncthreads();
    }

    const int bb = (int)(m0 / S_);
    float bq[4], vv[4];
    #pragma unroll
    for (int ni = 0; ni < 4; ++ni) {
        int u = n0 + wn * 64 + ni * 16 + lrow;
        bq[ni] = b1[u] + q2[bb * U_ + u];
        vv[ni] = V[u];
    }
    #pragma unroll
    for (int mi = 0; mi < 4; ++mi) {
        #pragma unroll
        for (int r = 0; r < 4; ++r) {
            float s = 0.f;
            #pragma unroll
            for (int ni = 0; ni < 4; ++ni) {
                float x = acc[mi][ni][r] + bq[ni];
                float t = 1.f - 2.f / (__expf(2.f * x) + 1.f);   // tanh
                s += t * vv[ni];
            }
            s += __shfl_xor(s, 1); s += __shfl_xor(s, 2);
            s += __shfl_xor(s, 4); s += __shfl_xor(s, 8);
            if (lrow == 0)
                atomicAdd(score + m0 + wm * 64 + mi * 16 + quad * 4 + r, s);
        }
    }
}

// ---------------- softmax over s, in place ----------------
__global__ void softmax_kernel(float* __restrict__ attn) {
    __shared__ float sh[S_];
    __shared__ float red[8];
    int b = blockIdx.x, tid = threadIdx.x;
    float* row = attn + (long)b * S_;
    float lmax = -1e30f;
    for (int i = tid; i < S_; i += 256) { float v = row[i]; sh[i] = v; lmax = fmaxf(lmax, v); }
    #pragma unroll
    for (int m = 32; m; m >>= 1) lmax = fmaxf(lmax, __shfl_xor(lmax, m));
    if ((tid & 63) == 0) red[tid >> 6] = lmax;
    __syncthreads();
    float gmax = fmaxf(fmaxf(red[0], red[1]), fmaxf(red[2], red[3]));
    float lsum = 0.f;
    for (int i = tid; i < S_; i += 256) { float e = __expf(sh[i] - gmax); sh[i] = e; lsum += e; }
    #pragma unroll
    for (int m = 32; m; m >>= 1) lsum += __shfl_xor(lsum, m);
    if ((tid & 63) == 0) red[4 + (tid >> 6)] = lsum;
    __syncthreads();
    float inv = 1.f / (red[4] + red[5] + red[6] + red[7]);
    for (int i = tid; i < S_; i += 256) row[i] = sh[i] * inv;
}

// ---------------- context = sum_s attn * values (fp32 direct) ----------------
__global__ void context_kernel(const float* __restrict__ vals, const float* __restrict__ attn,
                               float* __restrict__ ctx /* pre-zeroed */) {
    __shared__ float a_sh[128];
    int b = blockIdx.x >> 4;
    int sc = blockIdx.x & 15;
    int tid = threadIdx.x;
    if (tid < 128) a_sh[tid] = attn[(long)b * S_ + sc * 128 + tid];
    __syncthreads();
    const float* base = vals + ((long)b * S_ + sc * 128) * H_ + tid * 4;
    float ax = 0.f, ay = 0.f, az = 0.f, aw = 0.f;
    #pragma unroll 4
    for (int s = 0; s < 128; ++s) {
        float w = a_sh[s];
        float4 v = *reinterpret_cast<const float4*>(base + (long)s * H_);
        ax += w * v.x; ay += w * v.y; az += w * v.z; aw += w * v.w;
    }
    float* c = ctx + (long)b * H_ + tid * 4;
    atomicAdd(c + 0, ax); atomicAdd(c + 1, ay);
    atomicAdd(c + 2, az); atomicAdd(c + 3, aw);
}

extern "C" void kernel_launch(void* const* d_in, const int* in_sizes, int n_in,
                              void* d_out, int out_size, void* d_ws, size_t ws_size,
                              hipStream_t stream) {
    const float* query  = (const float*)d_in[0];
    const float* values = (const float*)d_in[1];
    const float* W1     = (const float*)d_in[2];
    const float* b1     = (const float*)d_in[3];
    const float* W2     = (const float*)d_in[4];
    const float* b2     = (const float*)d_in[5];
    const float* V      = (const float*)d_in[6];
    // d_in[7] = bv: softmax-invariant -> unused

    char* ws = (char*)d_ws;
    bf16*  w1t = (bf16*)ws;                                           // 2 MB
    float* q2  = (float*)(ws + (size_t)U_ * H_ * 2);                  // 128 KB
    bf16*  vbf = (bf16*)(ws + (size_t)U_ * H_ * 2 + (size_t)B_ * U_ * 4); // 128 MB
    const size_t need = (size_t)U_ * H_ * 2 + (size_t)B_ * U_ * 4
                      + (size_t)M_ * H_ * 2;

    float* ctx  = (float*)d_out;            // [B,H]
    float* attn = (float*)d_out + B_ * H_;  // [B,S]

    hipMemsetAsync(d_out, 0, (size_t)(B_ * H_ + B_ * S_) * sizeof(float), stream);

    if (ws_size >= need) {
        prep_kernel <<<768 + 4096, 256, 0, stream>>>(W1, w1t, query, W2, b2, q2, values, vbf);
        score_gemm8 <<<1024,       512, 0, stream>>>(vbf, w1t, b1, q2, V, attn);
    } else {
        prep_kernel <<<768,        256, 0, stream>>>(W1, w1t, query, W2, b2, q2, values, vbf);
        score_gemm  <<<(M_ / 128) * 8, 256, 0, stream>>>(values, w1t, b1, q2, V, attn);
    }
    softmax_kernel<<<B_,      256, 0, stream>>>(attn);
    context_kernel<<<B_ * 16, 256, 0, stream>>>(values, attn, ctx);
}

// Round 4
// 592.120 us; speedup vs baseline: 1.0297x; 1.0297x over previous
//
#include <hip/hip_runtime.h>
#include <hip/hip_bf16.h>

// BahdanauAttention: B=32, S=2048, H=1024, U=1024
//   q2 = query@W2 + b2                                  [B,U]
//   score[b,s] = sum_u tanh(values[b,s]@W1[:,u] + b1[u] + q2[b,u]) * V[u]
//   attn = softmax_s(score); context = sum_s attn * values
//
// R8 = R7 resubmit (R7 died to container infra, no signal; schedule re-audited:
// barriers uniform, vmcnt/lgkm ladders re-traced, no OOB, no LDS WAR).
// score_gemm8 inner loop m201-style interleave:
//  - fragment ds_reads pipelined one MFMA-cluster ahead (bg/af0 of tile t+1
//    read under MFMA1 of tile t; af1 of tile t read under MFMA0 of tile t)
//  - counted lgkmcnt(4)/lgkmcnt(8) per cluster, never 0 mid-loop
//  - ONE barrier per K-tile (was 2), fused with counted vmcnt(6)
//  - register double-buffer via named sets (static indexing, rule #20)
// R2 measured: 189us, MfmaUtil 31%, bank-conflict 0 (swizzle exact), FETCH 98MB.

#define B_ 32
#define S_ 2048
#define H_ 1024
#define U_ 1024
#define M_ (B_ * S_)   // 65536
#define NT_ 32         // K-tiles of 32 in score_gemm8

typedef __bf16 bf16;
typedef __bf16 bf16x8 __attribute__((ext_vector_type(8)));
typedef float  f32x4  __attribute__((ext_vector_type(4)));

__device__ __forceinline__ void gl2lds16(const void* g, void* l) {
    __builtin_amdgcn_global_load_lds(
        (const __attribute__((address_space(1))) void*)g,
        (__attribute__((address_space(3))) void*)l, 16, 0, 0);
}

__device__ __forceinline__ bf16x8 cvt8(float4 a, float4 b) {
    bf16x8 o;
    o[0] = (bf16)a.x; o[1] = (bf16)a.y; o[2] = (bf16)a.z; o[3] = (bf16)a.w;
    o[4] = (bf16)b.x; o[5] = (bf16)b.y; o[6] = (bf16)b.z; o[7] = (bf16)b.w;
    return o;
}

// ---------------- prep: W1 transpose-cast (0..255) + q2 (256..767) + values->bf16 (768..) ----
__global__ void prep_kernel(const float* __restrict__ W1, bf16* __restrict__ W1T,
                            const float* __restrict__ query, const float* __restrict__ W2,
                            const float* __restrict__ b2, float* __restrict__ q2,
                            const float* __restrict__ values, bf16* __restrict__ vbf) {
    __shared__ __align__(16) char smem[64 * 65 * 2];   // 8320 B, union of uses
    int tid = threadIdx.x;
    if (blockIdx.x < 256) {
        // ---- W1 [H,U] fp32 -> W1T [U,H] bf16 ----
        bf16* t = (bf16*)smem;
        int h0 = (blockIdx.x >> 4) * 64, u0 = (blockIdx.x & 15) * 64;
        #pragma unroll
        for (int i = 0; i < 16; ++i) {
            int idx = i * 256 + tid;
            int r = idx >> 6, c = idx & 63;
            t[c * 65 + r] = (bf16)W1[(long)(h0 + r) * U_ + u0 + c];
        }
        __syncthreads();
        #pragma unroll
        for (int i = 0; i < 16; ++i) {
            int idx = i * 256 + tid;
            int r = idx >> 6, c = idx & 63;
            W1T[(long)(u0 + r) * H_ + h0 + c] = t[r * 65 + c];
        }
    } else if (blockIdx.x < 768) {
        // ---- q2 = query@W2 + b2 ----
        float* qsh  = (float*)smem;            // 4 KB
        float* part = (float*)(smem + 4096);   // 4x64 f32 = 1 KB
        int idx = blockIdx.x - 256;            // 0..511
        int b  = idx >> 4;
        int u0 = (idx & 15) * 64;
        int ul = tid & 63, kc = tid >> 6;
        for (int i = tid; i < H_; i += 256) qsh[i] = query[b * H_ + i];
        __syncthreads();
        float acc = 0.f;
        const float* wp = W2 + (long)(kc * 256) * U_ + u0 + ul;
        #pragma unroll 8
        for (int h = 0; h < 256; ++h) acc += qsh[kc * 256 + h] * wp[(long)h * U_];
        part[kc * 64 + ul] = acc;
        __syncthreads();
        if (tid < 64)
            q2[b * U_ + u0 + tid] = part[tid] + part[64 + tid] + part[128 + tid]
                                    + part[192 + tid] + b2[u0 + tid];
    } else {
        // ---- values f32 [M,H] -> bf16 [M,H] ----
        long cid = (long)(blockIdx.x - 768) * 256 + tid;
        const long stride = 4096L * 256;
        const long n8 = (long)M_ * H_ / 8;     // 8M chunks of 8 elems
        for (long c = cid; c < n8; c += stride) {
            const float4* s = reinterpret_cast<const float4*>(values + c * 8);
            float4 a = s[0], b = s[1];
            *reinterpret_cast<bf16x8*>(vbf + c * 8) = cvt8(a, b);
        }
    }
}

// ---------------- fused GEMM + tanh + dot(V): 256x256 tile, BK=32, pipelined ------------
// 512 thr / 8 waves (2M x 4N), per-wave 128x64 C. LDS 128 KiB = 4 buffers x
// (A 16KB + B 16KB). Staging runs 3 K-tiles ahead; counted vmcnt(6) + ONE
// barrier per tile. Fragment reads pipelined one MFMA cluster ahead with
// counted lgkmcnt. 16B k-slots XOR-swizzled slot^=(row>>1)&3 via pre-swizzled
// GLOBAL source (linear LDS dest) + matching swizzled ds_read: 0 bank conflicts
// (verified R2).
__global__ __launch_bounds__(512, 2) void score_gemm8(
    const bf16* __restrict__ A,    // vbf [M,H]
    const bf16* __restrict__ BT,   // W1T bf16 [U,H]
    const float* __restrict__ b1, const float* __restrict__ q2,
    const float* __restrict__ V, float* __restrict__ score /* [M] pre-zeroed */)
{
    __shared__ __align__(16) bf16 lds[65536];          // 128 KiB
    const int tid  = threadIdx.x;
    const int lane = tid & 63;
    const int wave = tid >> 6;                         // 0..7
    const int wm = wave >> 2, wn = wave & 3;
    const int lrow = lane & 15, quad = lane >> 4;

    // XCD swizzle: 4 n-tiles of the same 256-row A-panel land consecutively on one XCD
    const int xcd = blockIdx.x & 7;
    const int j   = blockIdx.x >> 3;                   // 0..127
    const int mt  = xcd * 32 + (j >> 2);               // 0..255
    const int nt  = j & 3;
    const long m0 = (long)mt * 256;
    const int  n0 = nt * 256;

    // staging sources (per-lane, pre-swizzled): lane l covers (row wave*16+l/4, phys slot l&3)
    const int rs = wave * 16 + (lane >> 2);
    const int sl = (lane & 3) ^ ((lane >> 3) & 3);     // logical slot for phys slot l&3
    const bf16* ag0 = A  + (m0 + rs) * H_ + sl * 8;
    const bf16* ag1 = ag0 + 128 * H_;
    const bf16* bg0 = BT + (long)(n0 + rs) * H_ + sl * 8;
    const bf16* bg1 = bg0 + 128 * H_;

    // fragment read offsets (elems); kse applies the matching read-side swizzle
    const int kse  = (quad ^ ((lrow >> 1) & 3)) * 8;
    const int aoff = (wm * 128 + lrow) * 32 + kse;
    const int boff = 8192 + (wn * 64 + lrow) * 32 + kse;

    f32x4 acc[8][4];
    const f32x4 zero = {0.f, 0.f, 0.f, 0.f};
    #pragma unroll
    for (int mi = 0; mi < 8; ++mi)
        #pragma unroll
        for (int ni = 0; ni < 4; ++ni) acc[mi][ni] = zero;

    // prologue: stage tiles 0..2 into buffers 0..2 (12 loads), wait tile 0 (leave 8)
    for (int tt = 0; tt < 3; ++tt) {
        bf16* d = lds + tt * 16384 + wave * 512;
        gl2lds16(ag0 + tt * 32, d);
        gl2lds16(ag1 + tt * 32, d + 4096);
        gl2lds16(bg0 + tt * 32, d + 8192);
        gl2lds16(bg1 + tt * 32, d + 8192 + 4096);
    }
    __builtin_amdgcn_sched_barrier(0);
    asm volatile("s_waitcnt vmcnt(8)" ::: "memory");
    __builtin_amdgcn_s_barrier();
    __builtin_amdgcn_sched_barrier(0);

    // named register sets (static indexing): C = current tile, N = next tile
    bf16x8 bgA[4], a0A[4], bgB[4], a0B[4], af1[4];

    // preload tile 0 frags into set A (waited inside tile 0 ph0 via lgkm(4))
    #pragma unroll
    for (int ni = 0; ni < 4; ++ni)
        bgA[ni] = *reinterpret_cast<const bf16x8*>(lds + boff + ni * 512);
    #pragma unroll
    for (int mi = 0; mi < 4; ++mi)
        a0A[mi] = *reinterpret_cast<const bf16x8*>(lds + aoff + mi * 512);

#define TILE_BODY(T, bgC, a0C, bgN, a0N) do {                                   \
    const int t_ = (T);                                                         \
    const bf16* buf_ = lds + (t_ & 3) * 16384;                                  \
    /* ---- ph0: stage A(t+3); read af1 (this tile); MFMA0 on preloaded ---- */ \
    if (t_ + 3 < NT_) {                                                         \
        bf16* d_ = lds + ((t_ + 3) & 3) * 16384 + wave * 512;                   \
        gl2lds16(ag0 + (t_ + 3) * 32, d_);                                      \
        gl2lds16(ag1 + (t_ + 3) * 32, d_ + 4096);                               \
    }                                                                           \
    _Pragma("unroll")                                                           \
    for (int mi = 0; mi < 4; ++mi)                                              \
        af1[mi] = *reinterpret_cast<const bf16x8*>(buf_ + aoff + (4+mi) * 512); \
    asm volatile("s_waitcnt lgkmcnt(4)" ::: "memory");                          \
    __builtin_amdgcn_sched_barrier(0);                                          \
    __builtin_amdgcn_s_setprio(1);                                              \
    _Pragma("unroll")                                                           \
    for (int mi = 0; mi < 4; ++mi)                                              \
        _Pragma("unroll")                                                       \
        for (int ni = 0; ni < 4; ++ni)                                          \
            acc[mi][ni] = __builtin_amdgcn_mfma_f32_16x16x32_bf16(              \
                a0C[mi], bgC[ni], acc[mi][ni], 0, 0, 0);                        \
    __builtin_amdgcn_s_setprio(0);                                              \
    __builtin_amdgcn_sched_barrier(0);                                          \
    /* ---- mid: certify tile t+1 landed (counted), one barrier ---- */         \
    if (t_ < NT_ - 3)       asm volatile("s_waitcnt vmcnt(6)" ::: "memory");    \
    else if (t_ == NT_ - 3) asm volatile("s_waitcnt vmcnt(4)" ::: "memory");    \
    else if (t_ == NT_ - 2) asm volatile("s_waitcnt vmcnt(0)" ::: "memory");    \
    __builtin_amdgcn_s_barrier();                                               \
    __builtin_amdgcn_sched_barrier(0);                                          \
    /* ---- ph1: stage B(t+3); read next-tile bg/af0 under MFMA1 ---- */        \
    if (t_ + 3 < NT_) {                                                         \
        bf16* d_ = lds + ((t_ + 3) & 3) * 16384 + 8192 + wave * 512;            \
        gl2lds16(bg0 + (t_ + 3) * 32, d_);                                      \
        gl2lds16(bg1 + (t_ + 3) * 32, d_ + 4096);                               \
    }                                                                           \
    if (t_ + 1 < NT_) {                                                         \
        const bf16* nb_ = lds + ((t_ + 1) & 3) * 16384;                         \
        _Pragma("unroll")                                                       \
        for (int ni = 0; ni < 4; ++ni)                                          \
            bgN[ni] = *reinterpret_cast<const bf16x8*>(nb_ + boff + ni * 512);  \
        _Pragma("unroll")                                                       \
        for (int mi = 0; mi < 4; ++mi)                                          \
            a0N[mi] = *reinterpret_cast<const bf16x8*>(nb_ + aoff + mi * 512);  \
        asm volatile("s_waitcnt lgkmcnt(8)" ::: "memory");                      \
    } else {                                                                    \
        asm volatile("s_waitcnt lgkmcnt(0)" ::: "memory");                      \
    }                                                                           \
    __builtin_amdgcn_sched_barrier(0);                                          \
    __builtin_amdgcn_s_setprio(1);                                              \
    _Pragma("unroll")                                                           \
    for (int mi = 0; mi < 4; ++mi)                                              \
        _Pragma("unroll")                                                       \
        for (int ni = 0; ni < 4; ++ni)                                          \
            acc[4+mi][ni] = __builtin_amdgcn_mfma_f32_16x16x32_bf16(            \
                af1[mi], bgC[ni], acc[4+mi][ni], 0, 0, 0);                      \
    __builtin_amdgcn_s_setprio(0);                                              \
    __builtin_amdgcn_sched_barrier(0);                                          \
} while (0)

    #pragma unroll 1
    for (int tp = 0; tp < NT_; tp += 2) {
        TILE_BODY(tp,     bgA, a0A, bgB, a0B);   // even tile: consume A, preload B
        TILE_BODY(tp + 1, bgB, a0B, bgA, a0A);   // odd tile:  consume B, preload A
    }
#undef TILE_BODY

    // epilogue: tanh(acc + b1 + q2) * V, reduce over u (16 lanes), atomic into score
    const int bb = (int)(m0 / S_);
    float bq[4], vv[4];
    #pragma unroll
    for (int ni = 0; ni < 4; ++ni) {
        int u = n0 + wn * 64 + ni * 16 + lrow;
        bq[ni] = b1[u] + q2[bb * U_ + u];
        vv[ni] = V[u];
    }
    #pragma unroll
    for (int mi = 0; mi < 8; ++mi) {
        #pragma unroll
        for (int r = 0; r < 4; ++r) {
            float s = 0.f;
            #pragma unroll
            for (int ni = 0; ni < 4; ++ni) {
                float x = acc[mi][ni][r] + bq[ni];
                float th = 1.f - 2.f / (__expf(2.f * x) + 1.f);   // tanh
                s += th * vv[ni];
            }
            s += __shfl_xor(s, 1); s += __shfl_xor(s, 2);
            s += __shfl_xor(s, 4); s += __shfl_xor(s, 8);
            if (lrow == 0)
                atomicAdd(score + m0 + wm * 128 + mi * 16 + quad * 4 + r, s);
        }
    }
}

// ---------------- FALLBACK fused GEMM (proven R4 kernel, used when ws too small) ------------
#define ASTRIDE 40   // bf16 elems per A row in LDS (32 used + 8 pad)
__global__ __launch_bounds__(256, 3) void score_gemm(
    const float* __restrict__ A32,  // values fp32 [M,H]
    const bf16* __restrict__ BT,    // W1T bf16 [U,H]
    const float* __restrict__ b1, const float* __restrict__ q2,
    const float* __restrict__ V, float* __restrict__ score /* [M] pre-zeroed */)
{
    __shared__ __align__(16) bf16 a_sh[2 * 128 * ASTRIDE];   // 20 KB
    __shared__ __align__(16) bf16 b_sh[2 * 128 * 32];        // 16 KB
    const int tid  = threadIdx.x;
    const int lane = tid & 63;
    const int wave = tid >> 6;
    const int wm = wave >> 1, wn = wave & 1;
    const int xcd = blockIdx.x & 7;
    const int i_  = blockIdx.x >> 3;
    const int nt  = i_ & 7;
    const int mt  = xcd * 64 + (i_ >> 3);
    const long m0 = (long)mt * 128;
    const int  n0 = nt * 128;
    const int lrow = lane & 15;
    const int quad = lane >> 4;
    const int arow = tid >> 1;
    const int aseg = tid & 1;

    f32x4 acc[4][4];
    const f32x4 zero = {0.f, 0.f, 0.f, 0.f};
    #pragma unroll
    for (int mi = 0; mi < 4; ++mi)
        #pragma unroll
        for (int ni = 0; ni < 4; ++ni) acc[mi][ni] = zero;

    const float* Abase = A32 + m0 * H_;
    const bf16*  Bbase = BT + (long)n0 * H_;

    for (int kt = 0; kt < H_; kt += 64) {
        #pragma unroll
        for (int i = 0; i < 4; ++i) {
            int g  = i * 4 + wave;
            int hs = g >> 3, q = g & 7;
            int row = q * 16 + (lane >> 2);
            int gc  = (lane & 3) ^ ((row >> 1) & 3);
            gl2lds16(Bbase + (long)row * H_ + kt + hs * 32 + gc * 8,
                     (void*)(b_sh + hs * 4096 + q * 512));
        }
        float4 av[2][4];
        #pragma unroll
        for (int hs = 0; hs < 2; ++hs) {
            const float4* src = reinterpret_cast<const float4*>(
                Abase + (long)arow * H_ + kt + hs * 32 + aseg * 16);
            av[hs][0] = src[0]; av[hs][1] = src[1];
            av[hs][2] = src[2]; av[hs][3] = src[3];
        }
        #pragma unroll
        for (int hs = 0; hs < 2; ++hs) {
            bf16* dst = a_sh + hs * (128 * ASTRIDE) + arow * ASTRIDE + aseg * 16;
            *reinterpret_cast<bf16x8*>(dst)     = cvt8(av[hs][0], av[hs][1]);
            *reinterpret_cast<bf16x8*>(dst + 8) = cvt8(av[hs][2], av[hs][3]);
        }
        __syncthreads();

        #pragma unroll
        for (int hs = 0; hs < 2; ++hs) {
            bf16x8 af[4], bg[4];
            #pragma unroll
            for (int mi = 0; mi < 4; ++mi) {
                int r = wm * 64 + mi * 16 + lrow;
                af[mi] = *reinterpret_cast<const bf16x8*>(
                    a_sh + hs * (128 * ASTRIDE) + r * ASTRIDE + quad * 8);
            }
            #pragma unroll
            for (int ni = 0; ni < 4; ++ni) {
                int r = wn * 64 + ni * 16 + lrow;
                int p = quad ^ ((r >> 1) & 3);
                bg[ni] = *reinterpret_cast<const bf16x8*>(
                    b_sh + hs * 4096 + r * 32 + p * 8);
            }
            #pragma unroll
            for (int mi = 0; mi < 4; ++mi)
                #pragma unroll
                for (int ni = 0; ni < 4; ++ni)
                    acc[mi][ni] = __builtin_amdgcn_mfma_f32_16x16x32_bf16(
                        af[mi], bg[ni], acc[mi][ni], 0, 0, 0);
        }
        __syncthreads();
    }

    const int bb = (int)(m0 / S_);
    float bq[4], vv[4];
    #pragma unroll
    for (int ni = 0; ni < 4; ++ni) {
        int u = n0 + wn * 64 + ni * 16 + lrow;
        bq[ni] = b1[u] + q2[bb * U_ + u];
        vv[ni] = V[u];
    }
    #pragma unroll
    for (int mi = 0; mi < 4; ++mi) {
        #pragma unroll
        for (int r = 0; r < 4; ++r) {
            float s = 0.f;
            #pragma unroll
            for (int ni = 0; ni < 4; ++ni) {
                float x = acc[mi][ni][r] + bq[ni];
                float t = 1.f - 2.f / (__expf(2.f * x) + 1.f);   // tanh
                s += t * vv[ni];
            }
            s += __shfl_xor(s, 1); s += __shfl_xor(s, 2);
            s += __shfl_xor(s, 4); s += __shfl_xor(s, 8);
            if (lrow == 0)
                atomicAdd(score + m0 + wm * 64 + mi * 16 + quad * 4 + r, s);
        }
    }
}

// ---------------- softmax over s, in place ----------------
__global__ void softmax_kernel(float* __restrict__ attn) {
    __shared__ float sh[S_];
    __shared__ float red[8];
    int b = blockIdx.x, tid = threadIdx.x;
    float* row = attn + (long)b * S_;
    float lmax = -1e30f;
    for (int i = tid; i < S_; i += 256) { float v = row[i]; sh[i] = v; lmax = fmaxf(lmax, v); }
    #pragma unroll
    for (int m = 32; m; m >>= 1) lmax = fmaxf(lmax, __shfl_xor(lmax, m));
    if ((tid & 63) == 0) red[tid >> 6] = lmax;
    __syncthreads();
    float gmax = fmaxf(fmaxf(red[0], red[1]), fmaxf(red[2], red[3]));
    float lsum = 0.f;
    for (int i = tid; i < S_; i += 256) { float e = __expf(sh[i] - gmax); sh[i] = e; lsum += e; }
    #pragma unroll
    for (int m = 32; m; m >>= 1) lsum += __shfl_xor(lsum, m);
    if ((tid & 63) == 0) red[4 + (tid >> 6)] = lsum;
    __syncthreads();
    float inv = 1.f / (red[4] + red[5] + red[6] + red[7]);
    for (int i = tid; i < S_; i += 256) row[i] = sh[i] * inv;
}

// ---------------- context = sum_s attn * values (fp32 direct) ----------------
__global__ void context_kernel(const float* __restrict__ vals, const float* __restrict__ attn,
                               float* __restrict__ ctx /* pre-zeroed */) {
    __shared__ float a_sh[128];
    int b = blockIdx.x >> 4;
    int sc = blockIdx.x & 15;
    int tid = threadIdx.x;
    if (tid < 128) a_sh[tid] = attn[(long)b * S_ + sc * 128 + tid];
    __syncthreads();
    const float* base = vals + ((long)b * S_ + sc * 128) * H_ + tid * 4;
    float ax = 0.f, ay = 0.f, az = 0.f, aw = 0.f;
    #pragma unroll 4
    for (int s = 0; s < 128; ++s) {
        float w = a_sh[s];
        float4 v = *reinterpret_cast<const float4*>(base + (long)s * H_);
        ax += w * v.x; ay += w * v.y; az += w * v.z; aw += w * v.w;
    }
    float* c = ctx + (long)b * H_ + tid * 4;
    atomicAdd(c + 0, ax); atomicAdd(c + 1, ay);
    atomicAdd(c + 2, az); atomicAdd(c + 3, aw);
}

extern "C" void kernel_launch(void* const* d_in, const int* in_sizes, int n_in,
                              void* d_out, int out_size, void* d_ws, size_t ws_size,
                              hipStream_t stream) {
    const float* query  = (const float*)d_in[0];
    const float* values = (const float*)d_in[1];
    const float* W1     = (const float*)d_in[2];
    const float* b1     = (const float*)d_in[3];
    const float* W2     = (const float*)d_in[4];
    const float* b2     = (const float*)d_in[5];
    const float* V      = (const float*)d_in[6];
    // d_in[7] = bv: softmax-invariant -> unused

    char* ws = (char*)d_ws;
    bf16*  w1t = (bf16*)ws;                                           // 2 MB
    float* q2  = (float*)(ws + (size_t)U_ * H_ * 2);                  // 128 KB
    bf16*  vbf = (bf16*)(ws + (size_t)U_ * H_ * 2 + (size_t)B_ * U_ * 4); // 128 MB
    const size_t need = (size_t)U_ * H_ * 2 + (size_t)B_ * U_ * 4
                      + (size_t)M_ * H_ * 2;

    float* ctx  = (float*)d_out;            // [B,H]
    float* attn = (float*)d_out + B_ * H_;  // [B,S]

    hipMemsetAsync(d_out, 0, (size_t)(B_ * H_ + B_ * S_) * sizeof(float), stream);

    if (ws_size >= need) {
        prep_kernel <<<768 + 4096, 256, 0, stream>>>(W1, w1t, query, W2, b2, q2, values, vbf);
        score_gemm8 <<<1024,       512, 0, stream>>>(vbf, w1t, b1, q2, V, attn);
    } else {
        prep_kernel <<<768,        256, 0, stream>>>(W1, w1t, query, W2, b2, q2, values, vbf);
        score_gemm  <<<(M_ / 128) * 8, 256, 0, stream>>>(values, w1t, b1, q2, V, attn);
    }
    softmax_kernel<<<B_,      256, 0, stream>>>(attn);
    context_kernel<<<B_ * 16, 256, 0, stream>>>(values, attn, ctx);
}